// Round 6
// baseline (495.783 us; speedup 1.0000x reference)
//
#include <hip/hip_runtime.h>

#define N_NODES 100000
#define N_EDGES 1200000
#define D 64

#define BSHIFT 10
#define NB ((N_NODES + 1023) >> BSHIFT)        // 98 buckets of 1024 nodes
#define EPB 2048                                // edges per partition block
#define P1_BLOCKS ((N_EDGES + EPB - 1) / EPB)   // 586
#define P2_CAP 16384                            // per-bucket edge capacity

// ---------------- Phase 1a: per-bucket edge counts ---------------------------
__global__ __launch_bounds__(256) void p1_count(const int* __restrict__ row,
                                                int* __restrict__ bucketCount) {
  __shared__ int h[NB];
  const int t = threadIdx.x;
  for (int i = t; i < NB; i += 256) h[i] = 0;
  __syncthreads();
  const int base = blockIdx.x * EPB;
#pragma unroll
  for (int i = 0; i < EPB / 256; ++i) {
    int e = base + i * 256 + t;
    if (e < N_EDGES) atomicAdd(&h[row[e] >> BSHIFT], 1);
  }
  __syncthreads();
  for (int i = t; i < NB; i += 256)
    if (h[i]) atomicAdd(&bucketCount[i], h[i]);
}

// ---------------- Phase 1b: scan bucket counts -> starts + cursors ----------
__global__ __launch_bounds__(128) void p1_scan(const int* __restrict__ bucketCount,
                                               int* __restrict__ bucketStart,
                                               int* __restrict__ cursor) {
  __shared__ int lds[128];
  const int t = threadIdx.x;
  int v = (t < NB) ? bucketCount[t] : 0;
  lds[t] = v;
  __syncthreads();
  for (int off = 1; off < 128; off <<= 1) {
    int add = (t >= off) ? lds[t - off] : 0;
    __syncthreads();
    lds[t] += add;
    __syncthreads();
  }
  if (t < NB) {
    int start = lds[t] - v;
    bucketStart[t] = start;
    cursor[t] = start;
  }
  if (t == NB - 1) bucketStart[NB] = lds[t];
}

// ---------------- Phase 1c: partition (row,col) pairs into buckets -----------
__global__ __launch_bounds__(256) void p1_scatter(
    const int* __restrict__ row, const int* __restrict__ col,
    int* __restrict__ cursor, unsigned long long* __restrict__ pairBuf) {
  __shared__ int h[NB];
  __shared__ int hexcl[NB];
  __shared__ int gbase[NB];
  __shared__ int scan_lds[128];
  __shared__ unsigned long long staged[EPB];
  const int t = threadIdx.x;
  for (int i = t; i < NB; i += 256) h[i] = 0;
  __syncthreads();
  const int base = blockIdx.x * EPB;
  const int cnt = min(EPB, N_EDGES - base);

  int myrank[EPB / 256];
  int mybkt[EPB / 256];
  unsigned long long mypair[EPB / 256];
#pragma unroll
  for (int i = 0; i < EPB / 256; ++i) {
    int e = base + i * 256 + t;
    if (e < N_EDGES) {
      unsigned r = (unsigned)row[e];
      unsigned c = (unsigned)col[e];
      int b = (int)(r >> BSHIFT);
      mybkt[i] = b;
      mypair[i] = ((unsigned long long)r << 32) | c;
      myrank[i] = atomicAdd(&h[b], 1);
    } else {
      mybkt[i] = -1;
    }
  }
  __syncthreads();
  int v = 0;
  if (t < 128) { v = (t < NB) ? h[t] : 0; scan_lds[t] = v; }
  __syncthreads();
  for (int off = 1; off < 128; off <<= 1) {
    int add = (t >= off && t < 128) ? scan_lds[t - off] : 0;
    __syncthreads();
    if (t < 128) scan_lds[t] += add;
    __syncthreads();
  }
  if (t < NB) {
    hexcl[t] = scan_lds[t] - v;
    gbase[t] = (h[t] > 0) ? atomicAdd(&cursor[t], h[t]) : 0;
  }
  __syncthreads();
#pragma unroll
  for (int i = 0; i < EPB / 256; ++i)
    if (mybkt[i] >= 0) staged[hexcl[mybkt[i]] + myrank[i]] = mypair[i];
  __syncthreads();
  for (int i = t; i < cnt; i += 256) {
    unsigned long long p = staged[i];
    int b = (int)(p >> (32 + BSHIFT));
    pairBuf[gbase[b] + (i - hexcl[b])] = p;
  }
}

// ---------------- Phase 2: per-bucket local CSR ------------------------------
__global__ __launch_bounds__(1024) void p2_csr(
    const unsigned long long* __restrict__ pairBuf,
    const int* __restrict__ bucketStart,
    int* __restrict__ ends, int* __restrict__ sortedCol) {
  __shared__ int hist[1024];
  __shared__ int sc[1024];
  __shared__ unsigned short rankLDS[P2_CAP];
  const int t = threadIdx.x;
  const int b = blockIdx.x;
  const int base = bucketStart[b];
  const int cnt = min(bucketStart[b + 1] - base, P2_CAP);
  hist[t] = 0;
  __syncthreads();
  for (int i = t; i < cnt; i += 1024) {
    int lr = (int)((pairBuf[base + i] >> 32) & ((1 << BSHIFT) - 1));
    rankLDS[i] = (unsigned short)atomicAdd(&hist[lr], 1);
  }
  __syncthreads();
  int v = hist[t];
  sc[t] = v;
  __syncthreads();
  for (int off = 1; off < 1024; off <<= 1) {
    int add = (t >= off) ? sc[t - off] : 0;
    __syncthreads();
    sc[t] += add;
    __syncthreads();
  }
  const int node = (b << BSHIFT) + t;
  if (node < N_NODES) ends[node] = base + sc[t];
  const int excl = sc[t] - v;
  __syncthreads();
  sc[t] = excl;
  __syncthreads();
  for (int i = t; i < cnt; i += 1024) {
    unsigned long long p = pairBuf[base + i];
    int lr = (int)((p >> 32) & ((1 << BSHIFT) - 1));
    sortedCol[base + sc[lr] + (int)rankLDS[i]] = (int)(unsigned)p;
  }
}

// ---------------- Mean aggregation: one wave per node, float4 gathers --------
__global__ __launch_bounds__(256) void sage_agg(
    const float* __restrict__ xin, const int* __restrict__ ends,
    const int* __restrict__ sortedCol, float* __restrict__ agg, int n) {
  const int lane = threadIdx.x & 63;
  const int g = lane >> 4;
  const int fq = lane & 15;
  const int gwave = (blockIdx.x * blockDim.x + threadIdx.x) >> 6;
  const int nwaves = (gridDim.x * blockDim.x) >> 6;

  for (int r = gwave; r < n; r += nwaves) {
    const int start = (r == 0) ? 0 : ends[r - 1];
    const int end = ends[r];
    const int deg = end - start;
    float4 acc = make_float4(0.f, 0.f, 0.f, 0.f);

    for (int base = start; base < end; base += 64) {
      const int m = min(64, end - base);
      const int cv = (lane < m) ? sortedCol[base + lane] : 0;
      int j = 0;
      for (; j + 16 <= m; j += 16) {
        const int c0 = __shfl(cv, j + 0 + g);
        const int c1 = __shfl(cv, j + 4 + g);
        const int c2 = __shfl(cv, j + 8 + g);
        const int c3 = __shfl(cv, j + 12 + g);
        const float4 v0 = *(const float4*)(xin + (size_t)c0 * D + fq * 4);
        const float4 v1 = *(const float4*)(xin + (size_t)c1 * D + fq * 4);
        const float4 v2 = *(const float4*)(xin + (size_t)c2 * D + fq * 4);
        const float4 v3 = *(const float4*)(xin + (size_t)c3 * D + fq * 4);
        acc.x += (v0.x + v1.x) + (v2.x + v3.x);
        acc.y += (v0.y + v1.y) + (v2.y + v3.y);
        acc.z += (v0.z + v1.z) + (v2.z + v3.z);
        acc.w += (v0.w + v1.w) + (v2.w + v3.w);
      }
      for (; j < m; j += 4) {
        const int idx = j + g;
        const int c = __shfl(cv, (idx < m) ? idx : 0);
        if (idx < m) {
          const float4 v = *(const float4*)(xin + (size_t)c * D + fq * 4);
          acc.x += v.x; acc.y += v.y; acc.z += v.z; acc.w += v.w;
        }
      }
    }
    acc.x += __shfl_xor(acc.x, 16); acc.x += __shfl_xor(acc.x, 32);
    acc.y += __shfl_xor(acc.y, 16); acc.y += __shfl_xor(acc.y, 32);
    acc.z += __shfl_xor(acc.z, 16); acc.z += __shfl_xor(acc.z, 32);
    acc.w += __shfl_xor(acc.w, 16); acc.w += __shfl_xor(acc.w, 32);
    if (g == 0) {
      const float s = 1.0f / (float)max(deg, 1);
      float4 o;
      o.x = acc.x * s; o.y = acc.y * s; o.z = acc.z * s; o.w = acc.w * s;
      *(float4*)(agg + (size_t)r * D + fq * 4) = o;
    }
  }
}

// ---------------- Concat-matmul: out = act(b + x@Wtop + agg@Wbot) ------------
// Row-per-lane, feature-split-per-wave: wave w owns 64 rows x 32 features
// (half = w&1). W slice W[i][half*32..+32] is wave-uniform -> s_load into
// SGPRs; inner loop is pure v_fmac_f32(acc, s_w, v_x) with acc[32] in VGPRs.
// No readlanes, no 128-float per-lane array -> no spill.
__global__ __launch_bounds__(256) void sage_mm(
    const float* __restrict__ xin, const float* __restrict__ agg,
    const float* __restrict__ W, const float* __restrict__ b,
    float* __restrict__ out, int n, int doRelu) {
  const int lane = threadIdx.x & 63;
  const int gwave = (blockIdx.x * blockDim.x + threadIdx.x) >> 6;
  const int pair = gwave >> 1;       // 64-row group
  const int half = gwave & 1;        // feature half: [half*32, half*32+32)
  const int r = pair * 64 + lane;
  const bool live = (r < n);

  float acc[32];
  const float* bh = b + half * 32;
#pragma unroll
  for (int q = 0; q < 8; ++q) {
    const float4 bv = *((const float4*)bh + q);  // uniform -> s_load
    acc[q * 4 + 0] = bv.x; acc[q * 4 + 1] = bv.y;
    acc[q * 4 + 2] = bv.z; acc[q * 4 + 3] = bv.w;
  }

  const float* xrow = xin + (size_t)(live ? r : 0) * D;
  const float* arow = agg + (size_t)(live ? r : 0) * D;

  // self half: i = 0..63 uses W rows [0,64); agg half: W rows [64,128)
#pragma unroll 1
  for (int c = 0; c < 16; ++c) {
    const float4 xv = *(const float4*)(xrow + c * 4);
    const float xs[4] = {xv.x, xv.y, xv.z, xv.w};
#pragma unroll
    for (int k = 0; k < 4; ++k) {
      const float* wrow = W + (size_t)(c * 4 + k) * D + half * 32;  // uniform
#pragma unroll
      for (int q = 0; q < 8; ++q) {
        const float4 wv = *((const float4*)wrow + q);  // s_load
        acc[q * 4 + 0] = fmaf(xs[k], wv.x, acc[q * 4 + 0]);
        acc[q * 4 + 1] = fmaf(xs[k], wv.y, acc[q * 4 + 1]);
        acc[q * 4 + 2] = fmaf(xs[k], wv.z, acc[q * 4 + 2]);
        acc[q * 4 + 3] = fmaf(xs[k], wv.w, acc[q * 4 + 3]);
      }
    }
  }
#pragma unroll 1
  for (int c = 0; c < 16; ++c) {
    const float4 xv = *(const float4*)(arow + c * 4);
    const float xs[4] = {xv.x, xv.y, xv.z, xv.w};
#pragma unroll
    for (int k = 0; k < 4; ++k) {
      const float* wrow = W + (size_t)(64 + c * 4 + k) * D + half * 32;
#pragma unroll
      for (int q = 0; q < 8; ++q) {
        const float4 wv = *((const float4*)wrow + q);
        acc[q * 4 + 0] = fmaf(xs[k], wv.x, acc[q * 4 + 0]);
        acc[q * 4 + 1] = fmaf(xs[k], wv.y, acc[q * 4 + 1]);
        acc[q * 4 + 2] = fmaf(xs[k], wv.z, acc[q * 4 + 2]);
        acc[q * 4 + 3] = fmaf(xs[k], wv.w, acc[q * 4 + 3]);
      }
    }
  }

  if (live) {
    float* orow = out + (size_t)r * D + half * 32;
#pragma unroll
    for (int q = 0; q < 8; ++q) {
      float4 o;
      o.x = acc[q * 4 + 0]; o.y = acc[q * 4 + 1];
      o.z = acc[q * 4 + 2]; o.w = acc[q * 4 + 3];
      if (doRelu) {
        o.x = fmaxf(o.x, 0.f); o.y = fmaxf(o.y, 0.f);
        o.z = fmaxf(o.z, 0.f); o.w = fmaxf(o.w, 0.f);
      }
      *((float4*)orow + q) = o;
    }
  }
}

#define MM_PAIRS ((N_NODES + 63) / 64)               // 1563
#define MM_BLOCKS ((MM_PAIRS * 2 + 3) / 4)           // 782 blocks of 4 waves

extern "C" void kernel_launch(void* const* d_in, const int* in_sizes, int n_in,
                              void* d_out, int out_size, void* d_ws, size_t ws_size,
                              hipStream_t stream) {
  const float* x  = (const float*)d_in[0];
  const int*   ei = (const int*)d_in[1];
  const float* W1 = (const float*)d_in[2];
  const float* b1 = (const float*)d_in[3];
  const float* W2 = (const float*)d_in[4];
  const float* b2 = (const float*)d_in[5];
  float* out = (float*)d_out;

  const int* row = ei;            // edge_index[0]
  const int* col = ei + N_EDGES;  // edge_index[1]

  char* ws = (char*)d_ws;
  int* endsArr = (int*)ws;
  size_t off = ((size_t)N_NODES * sizeof(int) + 4095) & ~(size_t)4095;
  int* sortedCol = (int*)(ws + off);
  off += ((size_t)N_EDGES * sizeof(int) + 4095) & ~(size_t)4095;
  int* bucketCount = (int*)(ws + off);
  int* bucketStart = bucketCount + 128;
  int* cursor = bucketStart + 256;
  off += 4096;
  unsigned long long* pairBuf = (unsigned long long*)(ws + off);
  float* aggbuf = (float*)(ws + off);  // union: pairBuf dead before first sage_agg

  hipMemsetAsync(bucketCount, 0, NB * sizeof(int), stream);

  // ---- CSR build: bucketed two-phase partition ----
  p1_count<<<P1_BLOCKS, 256, 0, stream>>>(row, bucketCount);
  p1_scan<<<1, 128, 0, stream>>>(bucketCount, bucketStart, cursor);
  p1_scatter<<<P1_BLOCKS, 256, 0, stream>>>(row, col, cursor, pairBuf);
  p2_csr<<<NB, 1024, 0, stream>>>(pairBuf, bucketStart, endsArr, sortedCol);

  // ---- Layer 1: h = relu(concat(x, mean(x)) @ W1 + b1), h in d_out ----
  sage_agg<<<2048, 256, 0, stream>>>(x, endsArr, sortedCol, aggbuf, N_NODES);
  sage_mm<<<MM_BLOCKS, 256, 0, stream>>>(x, aggbuf, W1, b1, out, N_NODES, 1);

  // ---- Layer 2: out = concat(h, mean(h)) @ W2 + b2 (in place over h) ----
  sage_agg<<<2048, 256, 0, stream>>>(out, endsArr, sortedCol, aggbuf, N_NODES);
  sage_mm<<<MM_BLOCKS, 256, 0, stream>>>(out, aggbuf, W2, b2, out, N_NODES, 0);
}